// Round 1
// baseline (433.310 us; speedup 1.0000x reference)
//
#include <hip/hip_runtime.h>

// LinearSpline: per-channel scaled B1-spline lookup.
// x: [16, 64, 256, 256] fp32; coef: [64*129] fp32; scale: [64] fp32; zk: [64] int32.
// GRID = 0.0625 (exact power of 2), RANGE = 4.0, SIZE = 129 (odd -> no half-grid shift).
//
// Each block handles 4096 contiguous elements; since H*W = 65536 is a multiple
// of 4096, every block maps to exactly one channel -> one scale + one 129-entry
// coefficient table staged in LDS.

#define ELEMS_PER_BLOCK 4096

__global__ __launch_bounds__(256) void LinearSpline_kernel(
    const float* __restrict__ x,
    const float* __restrict__ coef,
    const float* __restrict__ scal,
    const int*   __restrict__ zk,
    float*       __restrict__ out)
{
    __shared__ float lds_c[129];
    __shared__ float s_scale[2];  // [0]=sc, [1]=1/sc

    const long long base = (long long)blockIdx.x * ELEMS_PER_BLOCK;
    const int c = (int)((base >> 16) & 63);  // channel: (idx / 65536) % 64

    if (threadIdx.x < 129) {
        // zero_knot_indexes[c] = c*129 + 64 -> table base = zk[c] - 64
        const int tb = zk[c] - 64;
        lds_c[threadIdx.x] = coef[tb + threadIdx.x];
    }
    if (threadIdx.x == 0) {
        const float sc = scal[c];
        s_scale[0] = sc;
        s_scale[1] = 1.0f / sc;
    }
    __syncthreads();

    const float sc = s_scale[0];
    const float rs = s_scale[1];

    const float4* __restrict__ xin = (const float4*)(x + base);
    float4*       __restrict__ xo  = (float4*)(out + base);

    #pragma unroll
    for (int it = 0; it < 4; ++it) {
        const int g = it * 256 + threadIdx.x;
        float4 v = xin[g];
        float4 r;
        float* vp = (float*)&v;
        float* rp = (float*)&r;
        #pragma unroll
        for (int j = 0; j < 4; ++j) {
            const float xs = vp[j] * sc;                       // xg (SIZE odd: no shift)
            const float xc = fminf(fmaxf(xs, -4.0f), 3.9375f); // clip to [-RANGE, RANGE-GRID]
            const float fl = floorf(xc * 16.0f);               // * (1/GRID), exact pow2
            const float fr = xs * 16.0f - fl;                  // fracs from UNclamped xg
            const int   k  = (int)fl + 64;                     // 0..127
            const float c0 = lds_c[k];
            const float c1 = lds_c[k + 1];
            rp[j] = (c1 * fr + c0 * (1.0f - fr) - 0.03125f) * rs;  // - GRID/2, / scale
        }
        xo[g] = r;
    }
}

extern "C" void kernel_launch(void* const* d_in, const int* in_sizes, int n_in,
                              void* d_out, int out_size, void* d_ws, size_t ws_size,
                              hipStream_t stream) {
    const float* x    = (const float*)d_in[0];
    const float* coef = (const float*)d_in[1];
    const float* scal = (const float*)d_in[2];
    const int*   zk   = (const int*)d_in[3];
    float*       out  = (float*)d_out;

    const int blocks = out_size / ELEMS_PER_BLOCK;  // 67108864 / 4096 = 16384
    LinearSpline_kernel<<<blocks, 256, 0, stream>>>(x, coef, scal, zk, out);
}

// Round 3
// 419.467 us; speedup vs baseline: 1.0330x; 1.0330x over previous
//
#include <hip/hip_runtime.h>

// LinearSpline: per-channel scaled B1-spline lookup.
// x: [16, 64, 256, 256] fp32; coef: [64*129] fp32; scale: [64] fp32; zk: [64] int32.
// GRID = 0.0625 (pow2 -> x/GRID == x*16 exactly), RANGE = 4.0, SIZE = 129 (odd).
//
// Each block handles 4096 contiguous elements -> exactly one channel.
// Per-block fused LDS table: tab[k] = { (c[k] - GRID/2)*rs , (c[k+1]-c[k])*rs }
// so the per-element epilogue is a single ds_read_b64 + fmaf.
// Clamp is done in the *16-scaled domain: clamp(xs,-4,3.9375)*16 ==
// clamp(xs*16,-64,63) exactly (pow2 scaling commutes with clamp).

#define ELEMS_PER_BLOCK 4096

typedef float v4f __attribute__((ext_vector_type(4)));  // native clang vector:
// __builtin_nontemporal_* requires scalar/vector-of-scalar pointee, not
// HIP_vector_type (a class).

__global__ __launch_bounds__(256) void LinearSpline_kernel(
    const float* __restrict__ x,
    const float* __restrict__ coef,
    const float* __restrict__ scal,
    const int*   __restrict__ zk,
    float*       __restrict__ out)
{
    __shared__ float2 tab[128];

    const long long base = (long long)blockIdx.x * ELEMS_PER_BLOCK;
    const int c = (int)((base >> 16) & 63);  // channel = (idx / 65536) % 64

    const float sc  = scal[c];        // block-uniform -> scalar load
    const float rs  = 1.0f / sc;
    const float s16 = sc * 16.0f;     // fold 1/GRID into the scale

    if (threadIdx.x < 128) {
        const int tb = zk[c] - 64;    // table base = c*129
        const float c0 = coef[tb + threadIdx.x];
        const float c1 = coef[tb + threadIdx.x + 1];
        tab[threadIdx.x] = make_float2((c0 - 0.03125f) * rs, (c1 - c0) * rs);
    }
    __syncthreads();

    const v4f* __restrict__ xin = (const v4f*)(x + base);
    v4f*       __restrict__ xo  = (v4f*)(out + base);

    auto ev = [&](float xv) -> float {
        const float t  = xv * s16;                       // xg / GRID (exact)
        const float tc = fminf(fmaxf(t, -64.0f), 63.0f); // clamp in scaled domain
        const float fl = floorf(tc);
        const float fr = t - fl;                         // fracs from UNclamped xg
        const int   k  = (int)fl + 64;                   // 0..127
        const float2 e = tab[k];
        return fmaf(fr, e.y, e.x);
    };

    #pragma unroll
    for (int it = 0; it < 4; ++it) {
        const int g = it * 256 + (int)threadIdx.x;
        v4f v = __builtin_nontemporal_load(&xin[g]);
        v4f r;
        r.x = ev(v.x);
        r.y = ev(v.y);
        r.z = ev(v.z);
        r.w = ev(v.w);
        __builtin_nontemporal_store(r, &xo[g]);
    }
}

extern "C" void kernel_launch(void* const* d_in, const int* in_sizes, int n_in,
                              void* d_out, int out_size, void* d_ws, size_t ws_size,
                              hipStream_t stream) {
    const float* x    = (const float*)d_in[0];
    const float* coef = (const float*)d_in[1];
    const float* scal = (const float*)d_in[2];
    const int*   zk   = (const int*)d_in[3];
    float*       out  = (float*)d_out;

    const int blocks = out_size / ELEMS_PER_BLOCK;  // 67108864 / 4096 = 16384
    LinearSpline_kernel<<<blocks, 256, 0, stream>>>(x, coef, scal, zk, out);
}